// Round 8
// baseline (531.252 us; speedup 1.0000x reference)
//
#include <hip/hip_runtime.h>
#include <hip/hip_bf16.h>
#include <math.h>
#include <cstdint>

typedef unsigned long long u64;
typedef unsigned int u32;
typedef _Float16 half8 __attribute__((ext_vector_type(8)));
typedef float floatx4 __attribute__((ext_vector_type(4)));

// ---------------------------------------------------------------------------
// Sizes
// ---------------------------------------------------------------------------
#define NANCH 36864        // 4096*9
#define SEG 65536          // per-image key segment stride
#define N_PRE 6000
#define N_POST 300
#define NW 96              // mask words per row (6144 bits)
#define NPADC 6144         // padded candidate count

// output float offsets
#define O0 0               // rpn_locs  2*36864*4 = 294912
#define O1 294912          // rpn_scores 2*36864*2 = 147456
#define O2 442368          // rois 2*300*4 = 2400
#define O3 444768          // roi_indices 600
#define O4 445368          // anchor 147456
#define O5 592824          // vmask 600

// workspace float offsets
#define WS_XHI   0                        // xhi f16 [2][4096][512] (2,097,152 f)
#define WS_XLO   2097152
#define WS_WHI   4194304                  // whi f16 [9][512][512] (1,179,648 f)
#define WS_WLO   5373952
#define WS_WSLT  6553600                  // 32768
#define WS_WSLB  6586368                  // 64
#define WS_H     6586432                  // hbuf f32 [2][4096][512] = 4,194,304 f
#define WS_GUARD 10780736                 // 64 floats of zeros (OOB target)
// overlays into dead XHI region (used only after conv completes):
#define WS_FG    0                        // 73728
#define WS_ROI   73728                    // 294912 (16B aligned)
#define WS_KEYS  368640                   // 131072 u64 = 262144 f
#define WS_SBOX  630784                   // 2*6144 float4 = 49152 f
#define WS_ALIVE 679936                   // 2*96 u64 = 384 f
#define WS_CKEYS 680320                   // 2*8192 u64 = 32768 f
#define WS_CNT   717184                   // 64 f
#define WS_CUT   717248                   // 64 f
// overlay into dead XLO region (after conv): 2^18-bin selection histogram
#define WS_HIST2 2097152                  // 2*262144 u32 = 524288 f
// overlay into dead WHI+WLO region (after conv): FULL suppression matrix
#define WS_MASK  4194304                  // 2*6144*96 u64 = 9,437,184 B (exact fit)

#define HSCALE 9.5367431640625e-07f       // 2^-20

// ---------------------------------------------------------------------------
__device__ __forceinline__ void gl_lds16(const void* g, void* l) {
  __builtin_amdgcn_global_load_lds(
      (const __attribute__((address_space(1))) u32*)g,
      (__attribute__((address_space(3))) u32*)l, 16, 0, 0);
}

__device__ __forceinline__ u64 bcast64(u64 v, int src) {
  u32 lo = (u32)__shfl((int)(v & 0xFFFFFFFFull), src);
  u32 hi = (u32)__shfl((int)(v >> 32), src);
  return ((u64)hi << 32) | lo;
}

// ---------------------------------------------------------------------------
// 0. fused prep: zero hbuf+guard | xcvt | wcvt | head-weight pack.
// ---------------------------------------------------------------------------
__global__ __launch_bounds__(256) void prep_all(
    const float* __restrict__ x, const float* __restrict__ w,
    const float* __restrict__ lw, const float* __restrict__ sw,
    const float* __restrict__ lb, const float* __restrict__ sb,
    float4* __restrict__ h, float4* __restrict__ guard,
    _Float16* __restrict__ xhi, _Float16* __restrict__ xlo,
    _Float16* __restrict__ whi, _Float16* __restrict__ wlo,
    float* __restrict__ wslt, float* __restrict__ wslb) {
  __shared__ float s[64 * 65];
  const int b = blockIdx.x, tid = threadIdx.x;
  if (b < 4097) {
    int idx = b * 256 + tid;
    if (idx < 1048576) h[idx] = make_float4(0.f, 0.f, 0.f, 0.f);
    else if (idx < 1048576 + 16) guard[idx - 1048576] = make_float4(0.f, 0.f, 0.f, 0.f);
    return;
  }
  if (b < 5121) {  // xcvt
    int l = b - 4097;
    int pt = l & 63, cg = (l >> 6) & 7, n = l >> 9;
    const int c0 = cg << 6, p0 = pt << 6;
#pragma unroll
    for (int kk = 0; kk < 16; ++kk) {
      int e = tid + (kk << 8);
      int ci = e >> 6, pi = e & 63;
      s[ci * 65 + pi] = x[(((size_t)(n * 512 + c0 + ci)) << 12) + p0 + pi];
    }
    __syncthreads();
#pragma unroll
    for (int kk = 0; kk < 16; ++kk) {
      int e = tid + (kk << 8);
      int ci = e & 63, pi = e >> 6;
      float sv = s[ci * 65 + pi] * 1024.f;
      _Float16 hi = (_Float16)sv;
      _Float16 lo = (_Float16)(sv - (float)hi);
      size_t off = (((size_t)(n << 12) + p0 + pi) << 9) + c0 + ci;
      xhi[off] = hi;
      xlo[off] = lo;
    }
    return;
  }
  if (b < 5697) {  // wcvt
    int l = b - 5121;
    int ct = l & 7, ot = (l >> 3) & 7, t = l >> 6;
    const int c0 = ct << 6, o0 = ot << 6;
#pragma unroll
    for (int kk = 0; kk < 16; ++kk) {
      int e = tid + (kk << 8);
      int ci = e & 63, oi = e >> 6;
      float sv = w[(size_t)(o0 + oi) * 4608 + (c0 + ci) * 9 + t] * 1024.f;
      _Float16 hi = (_Float16)sv;
      _Float16 lo = (_Float16)(sv - (float)hi);
      size_t off = ((size_t)((t << 9) + o0 + oi) << 9) + c0 + ci;
      whi[off] = hi;
      wlo[off] = lo;
    }
    return;
  }
  {  // prep_small
    int e = (b - 5697) * 256 + tid;
    if (e < 32768) {
      int c = e >> 6, o = e & 63;
      float v = 0.f;
      if (o < 36) v = lw[o * 512 + c];
      else if (o < 54) v = sw[(o - 36) * 512 + c];
      wslt[e] = v;
    } else if (e < 32832) {
      int o = e - 32768;
      float v = 0.f;
      if (o < 36) v = lb[o];
      else if (o < 54) v = sb[o - 36];
      wslb[o] = v;
    }
  }
}

// ---------------------------------------------------------------------------
// 1. MFMA implicit-GEMM 3x3 conv (fp16x2 split: hh + hl + lh, fp32 acc).
// k-slot swizzle -> conflict-free ds_read_b128. K-split x4.
// R6/R7 BUG (fixed): grid.z was 8 with kq = z&3 -> every block ran twice,
// atomic epilogue doubled hbuf. grid.z MUST equal the number of distinct kq.
// ---------------------------------------------------------------------------
__global__ __launch_bounds__(256) void conv_mfma(
    const _Float16* __restrict__ xhi, const _Float16* __restrict__ xlo,
    const _Float16* __restrict__ whi, const _Float16* __restrict__ wlo,
    const float* __restrict__ guard, float* __restrict__ hout) {
  __shared__ _Float16 aHi[4 * 68 * 32];
  __shared__ _Float16 aLo[4 * 68 * 32];
  __shared__ _Float16 bHi[128 * 32];
  __shared__ _Float16 bLo[128 * 32];
  const int tid = threadIdx.x;
  const int lane = tid & 63, w = tid >> 6;
  const int ptile = blockIdx.x;
  const int og = blockIdx.y;
  const int kq = blockIdx.z;           // 0..3 (grid.z == 4 exactly)
  const int y0 = (ptile & 31) << 1;
  const int nimg = ptile >> 5;
  const int o0 = og << 7;
  const int l15 = lane & 15, l16 = lane >> 4;
  const int ry = w >> 1;
  const int wo = (w & 1) << 6;

  floatx4 acc[4][4];
#pragma unroll
  for (int a = 0; a < 4; ++a)
#pragma unroll
    for (int b = 0; b < 4; ++b) acc[a][b] = (floatx4)0.f;

  for (int s = 0; s < 4; ++s) {
    const int c0 = (kq << 7) + (s << 5);
    __syncthreads();
    for (int i = w; i < 17; i += 4) {
      int chunk = (i << 6) + lane;
      int p = chunk >> 2;
      int q = ((chunk & 3) - ((chunk >> 3) & 3)) & 3;   // swizzled k-slot
      int r = p / 68, xs = p - r * 68;
      int y = y0 - 1 + r, xg = xs - 1;
      bool ok = ((unsigned)y < 64u) && ((unsigned)xg < 64u);
      size_t off = (((size_t)(nimg << 12) + (y << 6) + xg) << 9) + c0 + (q << 3);
      const void* gh = ok ? (const void*)(xhi + off) : (const void*)guard;
      const void* gl = ok ? (const void*)(xlo + off) : (const void*)guard;
      gl_lds16(gh, (char*)aHi + (i << 10));
      gl_lds16(gl, (char*)aLo + (i << 10));
    }
    for (int tt = 0; tt < 9; ++tt) {
      if (tt > 0) __syncthreads();
      for (int i = w; i < 8; i += 4) {
        int chunk = (i << 6) + lane;
        int row = chunk >> 2;
        int q = ((chunk & 3) - ((chunk >> 3) & 3)) & 3;  // swizzled k-slot
        size_t off = ((size_t)((tt << 9) + o0 + row) << 9) + c0 + (q << 3);
        gl_lds16((const void*)(whi + off), (char*)bHi + (i << 10));
        gl_lds16((const void*)(wlo + off), (char*)bLo + (i << 10));
      }
      __syncthreads();

      const int dy = tt / 3, dx = tt - 3 * dy;
      half8 ah[4], al[4], bh[4], bl[4];
#pragma unroll
      for (int im = 0; im < 4; ++im) {
        int xp = (im << 4) + l15;
        int P = (ry + dy) * 68 + xp + dx;
        int sw = ((l16 + (P >> 1)) & 3) << 3;
        ah[im] = *(const half8*)&aHi[(P << 5) + sw];
        al[im] = *(const half8*)&aLo[(P << 5) + sw];
      }
#pragma unroll
      for (int in = 0; in < 4; ++in) {
        int orow = wo + (in << 4) + l15;
        int swb = ((l16 + (orow >> 1)) & 3) << 3;
        bh[in] = *(const half8*)&bHi[(orow << 5) + swb];
        bl[in] = *(const half8*)&bLo[(orow << 5) + swb];
      }
#pragma unroll
      for (int im = 0; im < 4; ++im)
#pragma unroll
        for (int in = 0; in < 4; ++in) {
          acc[im][in] = __builtin_amdgcn_mfma_f32_16x16x32_f16(
              ah[im], bh[in], acc[im][in], 0, 0, 0);
          acc[im][in] = __builtin_amdgcn_mfma_f32_16x16x32_f16(
              ah[im], bl[in], acc[im][in], 0, 0, 0);
          acc[im][in] = __builtin_amdgcn_mfma_f32_16x16x32_f16(
              al[im], bh[in], acc[im][in], 0, 0, 0);
        }
    }
  }

#pragma unroll
  for (int im = 0; im < 4; ++im)
#pragma unroll
    for (int in = 0; in < 4; ++in) {
      int o = o0 + wo + (in << 4) + l15;
#pragma unroll
      for (int reg = 0; reg < 4; ++reg) {
        int m_local = (ry << 6) + (im << 4) + (l16 << 2) + reg;
        size_t off = (((size_t)(nimg << 12) + (y0 << 6) + m_local) << 9) + o;
        atomicAdd(&hout[off], acc[im][in][reg]);
      }
    }
}

// ---------------------------------------------------------------------------
// 2. 1x1 heads + softmax. grid (64 y, 2 n), block 256.
// Also inits overlay buffers: ckeys <- ~0, ghist2 <- 0, cnt <- 0.
// ---------------------------------------------------------------------------
__global__ __launch_bounds__(256) void head_kernel(
    const float* __restrict__ hbuf, const float* __restrict__ cb,
    const float* __restrict__ wslt, const float* __restrict__ wslb,
    float* __restrict__ out, float* __restrict__ fgbuf,
    float4* __restrict__ zkeys, float4* __restrict__ zhist,
    float4* __restrict__ zcnt) {
  const int y = blockIdx.x, n = blockIdx.y;
  __shared__ float sH[16 * 65];
  __shared__ float sWt[1024];
  __shared__ float sOut[64 * 65];
  const int tid = threadIdx.x;
  const int x = tid & 63, og = tid >> 6;
  const int bb = (n << 6) + y;   // 0..127

  {  // init overlays
    float f = __uint_as_float(0xFFFFFFFFu);
    if (tid < 64) zkeys[(bb << 6) + tid] = make_float4(f, f, f, f);
#pragma unroll
    for (int i = 0; i < 4; ++i)
      zhist[(bb << 10) + (i << 8) + tid] = make_float4(0.f, 0.f, 0.f, 0.f);
    if (bb == 0 && tid < 16) zcnt[tid] = make_float4(0.f, 0.f, 0.f, 0.f);
  }

  float acc[16];
#pragma unroll
  for (int j = 0; j < 16; ++j) acc[j] = 0.f;

  const float* hb = hbuf + (((size_t)(n << 12) + (y << 6)) << 9);

  const int cc4 = (tid & 3) << 2, xx = tid >> 2;
  for (int c0 = 0; c0 < 512; c0 += 16) {
    __syncthreads();
    {
      float4 v = *(const float4*)&hb[((size_t)xx << 9) + c0 + cc4];
      float4 bbv = *(const float4*)&cb[c0 + cc4];
      sH[(cc4 + 0) * 65 + xx] = fmaxf(v.x * HSCALE + bbv.x, 0.f);
      sH[(cc4 + 1) * 65 + xx] = fmaxf(v.y * HSCALE + bbv.y, 0.f);
      sH[(cc4 + 2) * 65 + xx] = fmaxf(v.z * HSCALE + bbv.z, 0.f);
      sH[(cc4 + 3) * 65 + xx] = fmaxf(v.w * HSCALE + bbv.w, 0.f);
      *(float4*)&sWt[tid << 2] = *(const float4*)&wslt[(c0 << 6) + (tid << 2)];
    }
    __syncthreads();
#pragma unroll
    for (int cc = 0; cc < 16; ++cc) {
      float hv = sH[cc * 65 + x];
      const float4* wp = (const float4*)&sWt[(cc << 6) + (og << 4)];
      float4 w0 = wp[0], w1 = wp[1], w2 = wp[2], w3 = wp[3];
      acc[0]  = fmaf(hv, w0.x, acc[0]);  acc[1]  = fmaf(hv, w0.y, acc[1]);
      acc[2]  = fmaf(hv, w0.z, acc[2]);  acc[3]  = fmaf(hv, w0.w, acc[3]);
      acc[4]  = fmaf(hv, w1.x, acc[4]);  acc[5]  = fmaf(hv, w1.y, acc[5]);
      acc[6]  = fmaf(hv, w1.z, acc[6]);  acc[7]  = fmaf(hv, w1.w, acc[7]);
      acc[8]  = fmaf(hv, w2.x, acc[8]);  acc[9]  = fmaf(hv, w2.y, acc[9]);
      acc[10] = fmaf(hv, w2.z, acc[10]); acc[11] = fmaf(hv, w2.w, acc[11]);
      acc[12] = fmaf(hv, w3.x, acc[12]); acc[13] = fmaf(hv, w3.y, acc[13]);
      acc[14] = fmaf(hv, w3.z, acc[14]); acc[15] = fmaf(hv, w3.w, acc[15]);
    }
  }
  __syncthreads();
#pragma unroll
  for (int j = 0; j < 16; ++j) {
    int o = (og << 4) + j;
    sOut[o * 65 + x] = acc[j] + wslb[o];
  }
  __syncthreads();

  const int p0 = (n << 12) + (y << 6);
  float* locs = out + O0 + (size_t)p0 * 36;
  for (int e = tid; e < 2304; e += 256) {
    int xp = e / 36, o = e - xp * 36;
    locs[e] = sOut[o * 65 + xp];
  }
  float* scrs = out + O1 + (size_t)p0 * 18;
  for (int e = tid; e < 1152; e += 256) {
    int xp = e / 18, ss = e - xp * 18;
    scrs[e] = sOut[(36 + ss) * 65 + xp];
  }
  float* fg = fgbuf + n * NANCH + (y << 6) * 9;
  for (int e = tid; e < 576; e += 256) {
    int xp = e / 9, a = e - xp * 9;
    float s0 = sOut[(36 + 2 * a) * 65 + xp];
    float s1 = sOut[(36 + 2 * a + 1) * 65 + xp];
    fg[e] = 1.0f / (1.0f + expf(s0 - s1));
  }
}

// ---------------------------------------------------------------------------
// 3. anchors + decode + clip + min-size + keys + 2^18-bin histogram of
// hi[31:14]. grid 288: n = b/144, k covers [0,36864) exactly.
// ---------------------------------------------------------------------------
__global__ __launch_bounds__(256) void decode_kernel(
    const float* __restrict__ out0, const float* __restrict__ fgbuf,
    float4* __restrict__ roibuf, u64* __restrict__ keys,
    float* __restrict__ anchor_out, float* __restrict__ out,
    u32* __restrict__ ghist,
    const int* __restrict__ imgh_p, const int* __restrict__ imgw_p) {
  const int tid = threadIdx.x, bb = blockIdx.x;
  const int n = bb / 144;
  const int k = (bb - n * 144) * 256 + tid;
  int gid = bb * 256 + tid;
  if (gid < 3600) {
    if (gid < 2400) out[O2 + gid] = 0.f;
    else if (gid < 3000) out[O3 + (gid - 2400)] = (float)((gid - 2400) / 300);
    else out[O5 + (gid - 3000)] = 0.f;
  }

  int a = k % 9;
  int p = k / 9;
  int py = p >> 6, px = p & 63;

  const double R[3] = {0.5, 1.0, 2.0};
  const double S[3] = {8.0, 16.0, 32.0};
  double r = R[a / 3], s = S[a - (a / 3) * 3];
  double hd = 16.0 * s * sqrt(r);
  double wd = 16.0 * s * sqrt(1.0 / r);
  float ay1 = (float)(8.0 - hd / 2.0) + (float)(py * 16);
  float ax1 = (float)(8.0 - wd / 2.0) + (float)(px * 16);
  float ay2 = (float)(8.0 + hd / 2.0) + (float)(py * 16);
  float ax2 = (float)(8.0 + wd / 2.0) + (float)(px * 16);
  if (n == 0) {
    float* ao = anchor_out + (size_t)k * 4;
    ao[0] = ay1; ao[1] = ax1; ao[2] = ay2; ao[3] = ax2;
  }
  float ahk = ay2 - ay1, awk = ax2 - ax1;
  float acy = ay1 + 0.5f * ahk, acx = ax1 + 0.5f * awk;
  const float* lp = out0 + ((size_t)(n * NANCH + k) << 2);
  float dy = lp[0], dx = lp[1], dh = lp[2], dw = lp[3];
  float cy = dy * ahk + acy;
  float cx = dx * awk + acx;
  float bh = expf(dh) * ahk;
  float bw = expf(dw) * awk;
  float img_h = (float)imgh_p[0], img_w = (float)imgw_p[0];
  float y1 = fminf(fmaxf(cy - 0.5f * bh, 0.f), img_h);
  float x1 = fminf(fmaxf(cx - 0.5f * bw, 0.f), img_w);
  float y2 = fminf(fmaxf(cy + 0.5f * bh, 0.f), img_h);
  float x2 = fminf(fmaxf(cx + 0.5f * bw, 0.f), img_w);
  bool valid = ((y2 - y1) >= 16.f) && ((x2 - x1) >= 16.f);
  float sc = valid ? fgbuf[n * NANCH + k] : -INFINITY;
  roibuf[n * NANCH + k] = make_float4(y1, x1, y2, x2);
  unsigned int b = __float_as_uint(sc);
  unsigned int m = b ^ ((b & 0x80000000u) ? 0xFFFFFFFFu : 0x80000000u);
  u32 hi = ~m;                        // ascending hi == descending score
  keys[(n << 16) + k] = ((u64)hi << 32) | (unsigned int)k;
  atomicAdd(&ghist[(n << 18) + (hi >> 14)], 1u);
}

// ---------------------------------------------------------------------------
// 4. cutoff-bin scan over 2^18 bins: one 1024-thread block per image.
// ---------------------------------------------------------------------------
__global__ __launch_bounds__(1024) void scan_cut(const u32* __restrict__ ghist,
                                                 u32* __restrict__ cut) {
  __shared__ u32 ps[1024];
  const int n = blockIdx.x, tid = threadIdx.x;
  const u32* h = ghist + (n << 18);
  u32 s = 0;
  const uint4* h4 = (const uint4*)(h + (tid << 8));
#pragma unroll
  for (int i = 0; i < 64; ++i) {
    uint4 v = h4[i];
    s += v.x + v.y + v.z + v.w;
  }
  ps[tid] = s;
  __syncthreads();
  for (int off = 1; off < 1024; off <<= 1) {
    u32 v = (tid >= off) ? ps[tid - off] : 0;
    __syncthreads();
    ps[tid] += v;
    __syncthreads();
  }
  u32 cumEnd = ps[tid], cumStart = cumEnd - s;
  if (cumStart < N_PRE && cumEnd >= N_PRE) {
    u32 c = cumStart;
    for (int i = 0; i < 256; ++i) {
      c += h[(tid << 8) + i];
      if (c >= N_PRE) { cut[n] = (tid << 8) + i; break; }
    }
  }
}

// ---------------------------------------------------------------------------
// 5. compact candidates with bin <= cut[n] into ckeys (<=8192 per image).
// ---------------------------------------------------------------------------
__global__ __launch_bounds__(256) void compact(
    const u64* __restrict__ keys, const u32* __restrict__ cut,
    u32* __restrict__ cnt, u64* __restrict__ ckeys) {
  const int b = blockIdx.x;
  const int n = b / 144;
  const int k = (b - n * 144) * 256 + threadIdx.x;
  u64 key = keys[(n << 16) + k];
  u32 bin = (u32)(key >> 46);         // hi[31:14]
  if (bin <= cut[n]) {
    u32 pos = atomicAdd(&cnt[n], 1u);
    if (pos < 8192) ckeys[(n << 13) + pos] = key;
  }
}

// ---------------------------------------------------------------------------
// 6. single-block bitonic sort of 8192 keys per image (64 KB LDS) + fused
// gather of sorted boxes + alive mask.
// ---------------------------------------------------------------------------
__global__ __launch_bounds__(1024) void sort8k(
    const u64* __restrict__ ckeys, const float4* __restrict__ roibuf,
    float4* __restrict__ sbox, u64* __restrict__ alive) {
  __shared__ u64 sk[8192];
  const int n = blockIdx.x, tid = threadIdx.x;
  for (int i = tid; i < 8192; i += 1024) sk[i] = ckeys[(n << 13) + i];
  __syncthreads();
  for (int k = 2; k <= 8192; k <<= 1) {
    for (int j = k >> 1; j > 0; j >>= 1) {
      for (int t = tid; t < 4096; t += 1024) {
        int l = ((t & ~(j - 1)) << 1) | (t & (j - 1));
        int rr = l | j;
        bool asc = ((l & k) == 0);
        u64 a = sk[l], b = sk[rr];
        if ((a > b) == asc) { sk[l] = b; sk[rr] = a; }
      }
      __syncthreads();
    }
  }
  for (int i = tid; i < NPADC; i += 1024) {
    u64 kk = sk[i];
    bool valid = (i < N_PRE) && (((u32)(kk >> 32)) < 0xFF800000u);
    float4 b = make_float4(0.f, 0.f, 0.f, 0.f);
    if (valid) b = roibuf[(size_t)n * NANCH + (u32)(kk & 0xFFFFFFFFull)];
    sbox[n * NPADC + i] = b;
    u64 bal = __ballot(valid);
    if ((tid & 63) == 0) alive[n * NW + (i >> 6)] = bal;
  }
}

// ---------------------------------------------------------------------------
// 7. build FULL suppression matrix (symmetric). grid (96, 4, 2), block 256.
// ---------------------------------------------------------------------------
__global__ __launch_bounds__(256) void build_mask(
    const float4* __restrict__ sbox, u64* __restrict__ M) {
  __shared__ float4 jb[4][64];
  __shared__ float ja[4][64];
  const int tid = threadIdx.x, lane = tid & 63, wv = tid >> 6;
  const int g = blockIdx.x, q = blockIdx.y, n = blockIdx.z;
  const float4* sb = sbox + n * NPADC;
  float4 bi = sb[(g << 6) + lane];
  float ai = (bi.z - bi.x) * (bi.w - bi.y);
  u64* Mrow = M + ((size_t)(n * NPADC + (g << 6) + lane)) * NW;
#pragma unroll
  for (int it = 0; it < 6; ++it) {
    int w = q * 24 + (it << 2) + wv;
    float4 bjl = sb[(w << 6) + lane];
    jb[wv][lane] = bjl;
    ja[wv][lane] = (bjl.z - bjl.x) * (bjl.w - bjl.y);
    u64 bits = 0;
#pragma unroll 8
    for (int j = 0; j < 64; ++j) {
      float4 bj = jb[wv][j];
      float aj = ja[wv][j];
      float ih = fmaxf(fminf(bi.z, bj.z) - fmaxf(bi.x, bj.x), 0.f);
      float iw = fmaxf(fminf(bi.w, bj.w) - fmaxf(bi.y, bj.y), 0.f);
      float inter = ih * iw;
      bool bit = inter / (ai + aj - inter + 1e-9f) > 0.7f;
      bits |= ((u64)bit) << j;
    }
    Mrow[w] = bits;
  }
}

// ---------------------------------------------------------------------------
// 8. serial greedy reduce, one wave per image (rolling prefetch + 8-wide
// batched OR loads).
// ---------------------------------------------------------------------------
__global__ __launch_bounds__(64) void nms_reduce(
    const u64* __restrict__ M, const u64* __restrict__ alive,
    const float4* __restrict__ sbox, float* __restrict__ out) {
  const int n = blockIdx.x, lane = threadIdx.x;
  float* rois = out + O2 + n * (N_POST * 4);
  float* vmask = out + O5 + n * N_POST;
  const u64* A = alive + n * NW;
  const u64* Mb = M + (size_t)n * NPADC * NW;
  const float4* sb = sbox + n * NPADC;
  u64 aw0 = A[lane];
  u64 aw1 = (lane < 32) ? A[64 + lane] : 0ull;
  u64 accA = 0, accB = 0;
  int nk = 0;
  u64 dnext = Mb[(size_t)lane * NW + 0];
  float4 bnext = sb[lane];
  const u64 below = lane ? (~0ull >> (64 - lane)) : 0ull;

  for (int c = 0; c < 94; ++c) {
    u64 dcur = dnext;
    float4 bcur = bnext;
    if (c + 1 < 94) {
      dnext = Mb[(size_t)(((c + 1) << 6) + lane) * NW + (c + 1)];
      bnext = sb[((c + 1) << 6) + lane];
    }
    u64 wacc = (c < 64) ? bcast64(accA, c) : bcast64(accB, c - 64);
    u64 aw = (c < 64) ? bcast64(aw0, c) : bcast64(aw1, c - 64);
    u64 alive_u = aw & ~wacc;
    if (alive_u == 0ull) continue;

    u64 dmask = dcur & below;
    u64 rem = alive_u, kept = 0;
    while (rem) {
      int j = __builtin_ctzll(rem);
      kept |= 1ull << j;
      u64 col = __ballot((dmask >> j) & 1);
      rem &= ~(col | (1ull << j));
    }

    int npop = __popcll(kept);
    if ((kept >> lane) & 1ull) {
      int slot = nk + __popcll(kept & below);
      if (slot < N_POST) {
        rois[slot * 4 + 0] = bcur.x; rois[slot * 4 + 1] = bcur.y;
        rois[slot * 4 + 2] = bcur.z; rois[slot * 4 + 3] = bcur.w;
        vmask[slot] = 1.0f;
      }
    }
    if (nk + npop >= N_POST) break;
    nk += npop;

    u64 kk = kept;
    while (kk) {
      int j0 = __builtin_ctzll(kk); kk &= kk - 1;
      int j1 = kk ? __builtin_ctzll(kk) : j0; kk &= kk - 1;
      int j2 = kk ? __builtin_ctzll(kk) : j0; kk &= kk - 1;
      int j3 = kk ? __builtin_ctzll(kk) : j0; kk &= kk - 1;
      int j4 = kk ? __builtin_ctzll(kk) : j0; kk &= kk - 1;
      int j5 = kk ? __builtin_ctzll(kk) : j0; kk &= kk - 1;
      int j6 = kk ? __builtin_ctzll(kk) : j0; kk &= kk - 1;
      int j7 = kk ? __builtin_ctzll(kk) : j0; kk &= kk - 1;
      const u64* r0 = Mb + (size_t)((c << 6) + j0) * NW;
      const u64* r1 = Mb + (size_t)((c << 6) + j1) * NW;
      const u64* r2 = Mb + (size_t)((c << 6) + j2) * NW;
      const u64* r3 = Mb + (size_t)((c << 6) + j3) * NW;
      const u64* r4 = Mb + (size_t)((c << 6) + j4) * NW;
      const u64* r5 = Mb + (size_t)((c << 6) + j5) * NW;
      const u64* r6 = Mb + (size_t)((c << 6) + j6) * NW;
      const u64* r7 = Mb + (size_t)((c << 6) + j7) * NW;
      u64 oA = r0[lane] | r1[lane] | r2[lane] | r3[lane]
             | r4[lane] | r5[lane] | r6[lane] | r7[lane];
      u64 oB = 0;
      if (lane < 32)
        oB = r0[64 + lane] | r1[64 + lane] | r2[64 + lane] | r3[64 + lane]
           | r4[64 + lane] | r5[64 + lane] | r6[64 + lane] | r7[64 + lane];
      accA |= oA;
      accB |= oB;
    }
  }
}

// ---------------------------------------------------------------------------
extern "C" void kernel_launch(void* const* d_in, const int* in_sizes, int n_in,
                              void* d_out, int out_size, void* d_ws, size_t ws_size,
                              hipStream_t stream) {
  const float* x        = (const float*)d_in[0];
  const float* conv1_w  = (const float*)d_in[1];
  const float* conv1_b  = (const float*)d_in[2];
  const float* score_w  = (const float*)d_in[3];
  const float* score_b  = (const float*)d_in[4];
  const float* loc_w    = (const float*)d_in[5];
  const float* loc_b    = (const float*)d_in[6];
  const int*   imgh_p   = (const int*)d_in[7];
  const int*   imgw_p   = (const int*)d_in[8];

  float* out = (float*)d_out;
  float* ws  = (float*)d_ws;

  _Float16* xhi = (_Float16*)(ws + WS_XHI);
  _Float16* xlo = (_Float16*)(ws + WS_XLO);
  _Float16* whi = (_Float16*)(ws + WS_WHI);
  _Float16* wlo = (_Float16*)(ws + WS_WLO);
  float* wslt   = ws + WS_WSLT;
  float* wslb   = ws + WS_WSLB;
  float* hbuf   = ws + WS_H;
  float* guard  = ws + WS_GUARD;
  // overlays (xhi/xlo/whi/wlo regions dead after conv)
  float* fgbuf   = ws + WS_FG;
  float4* roibuf = (float4*)(ws + WS_ROI);
  u64* keys      = (u64*)(ws + WS_KEYS);
  float4* sbox   = (float4*)(ws + WS_SBOX);
  u64* alive     = (u64*)(ws + WS_ALIVE);
  u64* ckeys     = (u64*)(ws + WS_CKEYS);
  u32* cnt       = (u32*)(ws + WS_CNT);
  u32* cut       = (u32*)(ws + WS_CUT);
  u32* ghist     = (u32*)(ws + WS_HIST2);  // overlays xlo
  u64* maskbuf   = (u64*)(ws + WS_MASK);   // overlays whi/wlo

  prep_all<<<5826, 256, 0, stream>>>(x, conv1_w, loc_w, score_w, loc_b, score_b,
                                     (float4*)hbuf, (float4*)guard,
                                     xhi, xlo, whi, wlo, wslt, wslb);

  conv_mfma<<<dim3(64, 4, 4), 256, 0, stream>>>(xhi, xlo, whi, wlo, guard, hbuf);

  head_kernel<<<dim3(64, 2), 256, 0, stream>>>(hbuf, conv1_b, wslt, wslb, out,
                                               fgbuf, (float4*)ckeys,
                                               (float4*)ghist, (float4*)cnt);
  decode_kernel<<<288, 256, 0, stream>>>(out, fgbuf, roibuf, keys,
                                         out + O4, out, ghist, imgh_p, imgw_p);
  scan_cut<<<2, 1024, 0, stream>>>(ghist, cut);
  compact<<<288, 256, 0, stream>>>(keys, cut, cnt, ckeys);
  sort8k<<<2, 1024, 0, stream>>>(ckeys, roibuf, sbox, alive);

  build_mask<<<dim3(96, 4, 2), 256, 0, stream>>>(sbox, maskbuf);
  nms_reduce<<<2, 64, 0, stream>>>(maskbuf, alive, sbox, out);
}